// Round 1
// baseline (2274.210 us; speedup 1.0000x reference)
//
#include <hip/hip_runtime.h>

#define N 4096
#define REG_E 0.05f
#define NITER 100

// ---------------- transpose + max ----------------
__global__ __launch_bounds__(256) void transpose_max_k(const float* __restrict__ C,
                                                       float* __restrict__ Ct,
                                                       float* __restrict__ maxC) {
    __shared__ float tile[64][65];
    const int bx = blockIdx.x & 63;   // col tile
    const int by = blockIdx.x >> 6;   // row tile
    const int t  = threadIdx.x;
    const int tx = t & 15;            // float4 slot along 64 cols
    const int ty = t >> 4;            // 0..15
    const int c0 = bx * 64, r0 = by * 64;

    float m = 0.f;
#pragma unroll
    for (int k = 0; k < 4; ++k) {
        int r = ty + k * 16;
        float4 v = *(const float4*)(C + (size_t)(r0 + r) * N + c0 + tx * 4);
        tile[r][tx * 4 + 0] = v.x;
        tile[r][tx * 4 + 1] = v.y;
        tile[r][tx * 4 + 2] = v.z;
        tile[r][tx * 4 + 3] = v.w;
        m = fmaxf(m, fmaxf(fmaxf(v.x, v.y), fmaxf(v.z, v.w)));
    }
    __syncthreads();
#pragma unroll
    for (int k = 0; k < 4; ++k) {
        int i = ty + k * 16;  // row in Ct tile == original col
        float4 w;
        w.x = tile[tx * 4 + 0][i];
        w.y = tile[tx * 4 + 1][i];
        w.z = tile[tx * 4 + 2][i];
        w.w = tile[tx * 4 + 3][i];
        *(float4*)(Ct + (size_t)(c0 + i) * N + r0 + tx * 4) = w;
    }
    // block max reduce
#pragma unroll
    for (int off = 32; off; off >>= 1) m = fmaxf(m, __shfl_down(m, off));
    __shared__ float wm[4];
    if ((t & 63) == 0) wm[t >> 6] = m;
    __syncthreads();
    if (t == 0) {
        m = fmaxf(fmaxf(wm[0], wm[1]), fmaxf(wm[2], wm[3]));
        atomicMax((int*)maxC, __float_as_int(m));  // all C >= 0
    }
}

// ---------------- max only (fallback, no transpose) ----------------
__global__ __launch_bounds__(256) void max_k(const float* __restrict__ C, float* __restrict__ maxC) {
    const float4* C4 = (const float4*)C;
    const size_t n4 = (size_t)N * N / 4;
    float m = 0.f;
    for (size_t i = (size_t)blockIdx.x * 256 + threadIdx.x; i < n4; i += (size_t)gridDim.x * 256) {
        float4 c = C4[i];
        m = fmaxf(m, fmaxf(fmaxf(c.x, c.y), fmaxf(c.z, c.w)));
    }
#pragma unroll
    for (int off = 32; off; off >>= 1) m = fmaxf(m, __shfl_down(m, off));
    __shared__ float wm[4];
    if ((threadIdx.x & 63) == 0) wm[threadIdx.x >> 6] = m;
    __syncthreads();
    if (threadIdx.x == 0) {
        m = fmaxf(fmaxf(wm[0], wm[1]), fmaxf(wm[2], wm[3]));
        atomicMax((int*)maxC, __float_as_int(m));
    }
}

// ---------------- small init: logp, logq, scale ----------------
__global__ __launch_bounds__(256) void init_k(const float* __restrict__ p, const float* __restrict__ q,
                                              float* __restrict__ logp, float* __restrict__ logq,
                                              float* __restrict__ scale, const float* __restrict__ maxC) {
    int i = blockIdx.x * 256 + threadIdx.x;
    if (i < N) {
        logp[i] = __logf(p[i]);
        logq[i] = __logf(q[i]);
    }
    if (i == 0) *scale = -1.0f / (*maxC * REG_E);
}

// ---------------- one LSE pass over a row-major NxN matrix ----------------
// out[row] = logw[row] - log( sum_j exp( M[row][j]*scale + other[j] ) )
__global__ __launch_bounds__(256) void lse_pass(const float* __restrict__ M,
                                                const float* __restrict__ other,
                                                const float* __restrict__ logw,
                                                float* __restrict__ outpot,
                                                const float* __restrict__ scale_p) {
    const float scale = *scale_p;
    const int row = blockIdx.x;
    const int t = threadIdx.x;
    const float4* Mrow = (const float4*)(M + (size_t)row * N);
    const float4* ov = (const float4*)other;

    float s = 0.f;
#pragma unroll
    for (int k = 0; k < 4; ++k) {
        float4 c = Mrow[t + k * 256];
        float4 w = ov[t + k * 256];
        s += __expf(fmaf(c.x, scale, w.x));
        s += __expf(fmaf(c.y, scale, w.y));
        s += __expf(fmaf(c.z, scale, w.z));
        s += __expf(fmaf(c.w, scale, w.w));
    }
#pragma unroll
    for (int off = 32; off; off >>= 1) s += __shfl_down(s, off);
    __shared__ float ls[4];
    if ((t & 63) == 0) ls[t >> 6] = s;
    __syncthreads();
    if (t == 0) {
        float tot = (ls[0] + ls[1]) + (ls[2] + ls[3]);
        outpot[row] = logw[row] - __logf(tot);
    }
}

// ---------------- fallback col pass: atomic partial sums + last-block finalize ----------------
__global__ __launch_bounds__(256) void col_pass_atomic(const float* __restrict__ C,
                                                       const float* __restrict__ u,
                                                       const float* __restrict__ logq,
                                                       float* __restrict__ v,
                                                       float* __restrict__ acc,
                                                       unsigned* __restrict__ counter,
                                                       const float* __restrict__ scale_p) {
    const float scale = *scale_p;
    const int stripe = blockIdx.x & 3;   // 4 stripes of 1024 cols
    const int chunk = blockIdx.x >> 2;   // 64 chunks of 64 rows
    const int t = threadIdx.x;
    const int c0 = stripe * 1024 + t * 4;
    const int r0 = chunk * 64;

    float s0 = 0.f, s1 = 0.f, s2 = 0.f, s3 = 0.f;
    for (int r = 0; r < 64; ++r) {
        float ur = u[r0 + r];
        float4 c = *(const float4*)(C + (size_t)(r0 + r) * N + c0);
        s0 += __expf(fmaf(c.x, scale, ur));
        s1 += __expf(fmaf(c.y, scale, ur));
        s2 += __expf(fmaf(c.z, scale, ur));
        s3 += __expf(fmaf(c.w, scale, ur));
    }
    atomicAdd(&acc[c0 + 0], s0);
    atomicAdd(&acc[c0 + 1], s1);
    atomicAdd(&acc[c0 + 2], s2);
    atomicAdd(&acc[c0 + 3], s3);
    __threadfence();
    __shared__ bool isLast;
    if (t == 0) isLast = (atomicAdd(counter, 1u) == 255u);
    __syncthreads();
    if (isLast) {
        __threadfence();
        for (int j = t; j < N; j += 256) {
            v[j] = logq[j] - __logf(acc[j]);
            acc[j] = 0.f;
        }
        if (t == 0) *counter = 0u;
    }
}

// ---------------- final plan ----------------
__global__ __launch_bounds__(256) void final_k(const float* __restrict__ C,
                                               const float* __restrict__ u,
                                               const float* __restrict__ v,
                                               const float* __restrict__ scale_p,
                                               float* __restrict__ out) {
    const float scale = *scale_p;
    const size_t i4 = (size_t)blockIdx.x * 256 + threadIdx.x;  // over N*N/4 float4s
    const float4* C4 = (const float4*)C;
    float4* O4 = (float4*)out;
    float4 c = C4[i4];
    int row = (int)(i4 >> 10);          // N/4 = 1024 float4s per row
    int v4i = (int)(i4 & 1023);
    float uv = u[row];
    const float4 vv = ((const float4*)v)[v4i];
    float4 o;
    o.x = __expf(fmaf(c.x, scale, uv + vv.x));
    o.y = __expf(fmaf(c.y, scale, uv + vv.y));
    o.z = __expf(fmaf(c.z, scale, uv + vv.z));
    o.w = __expf(fmaf(c.w, scale, uv + vv.w));
    O4[i4] = o;
}

extern "C" void kernel_launch(void* const* d_in, const int* in_sizes, int n_in,
                              void* d_out, int out_size, void* d_ws, size_t ws_size,
                              hipStream_t stream) {
    const float* p = (const float*)d_in[0];
    const float* q = (const float*)d_in[1];
    const float* C = (const float*)d_in[2];
    float* out = (float*)d_out;

    float* W = (float*)d_ws;
    float* maxC = W + 0;
    float* scale = W + 1;
    unsigned* counter = (unsigned*)(W + 2);
    float* u = W + 4;
    float* v = u + N;
    float* logp = v + N;
    float* logq = logp + N;
    float* acc = logq + N;

    const size_t HDR = 128 * 1024;  // bytes reserved for header; Ct starts here
    float* Ct = (float*)((char*)d_ws + HDR);
    const bool useT = ws_size >= HDR + (size_t)N * N * sizeof(float);

    // zero header: maxC, scale, counter, u, v(=v0), logp, logq, acc
    size_t hdr_used = (4 + 5 * (size_t)N) * sizeof(float);
    hipMemsetAsync(d_ws, 0, hdr_used, stream);

    if (useT)
        transpose_max_k<<<4096, 256, 0, stream>>>(C, Ct, maxC);
    else
        max_k<<<2048, 256, 0, stream>>>(C, maxC);

    init_k<<<16, 256, 0, stream>>>(p, q, logp, logq, scale, maxC);

    for (int it = 0; it < NITER; ++it) {
        // u = logp - LSE_row(Mr + v)
        lse_pass<<<N, 256, 0, stream>>>(C, v, logp, u, scale);
        // v = logq - LSE_col(Mr + u)
        if (useT)
            lse_pass<<<N, 256, 0, stream>>>(Ct, u, logq, v, scale);
        else
            col_pass_atomic<<<256, 256, 0, stream>>>(C, u, logq, v, acc, counter, scale);
    }

    final_k<<<16384, 256, 0, stream>>>(C, u, v, scale, out);
}

// Round 2
// 1548.701 us; speedup vs baseline: 1.4685x; 1.4685x over previous
//
#include <hip/hip_runtime.h>

#define N 4096
#define NITER 100
// Mr = -(C/maxC)/0.05 in [-20,0]; q = round((C/maxC)*65535); Mr ~= -q*DSTEP
#define DSTEP (20.0f / 65535.0f)

// ---------------- global max of C ----------------
__global__ __launch_bounds__(256) void max_k(const float* __restrict__ C, float* __restrict__ maxC) {
    const float4* C4 = (const float4*)C;
    const size_t n4 = (size_t)N * N / 4;
    float m = 0.f;
    for (size_t i = (size_t)blockIdx.x * 256 + threadIdx.x; i < n4; i += (size_t)gridDim.x * 256) {
        float4 c = C4[i];
        m = fmaxf(m, fmaxf(fmaxf(c.x, c.y), fmaxf(c.z, c.w)));
    }
#pragma unroll
    for (int off = 32; off; off >>= 1) m = fmaxf(m, __shfl_down(m, off));
    __shared__ float wm[4];
    if ((threadIdx.x & 63) == 0) wm[threadIdx.x >> 6] = m;
    __syncthreads();
    if (threadIdx.x == 0) {
        m = fmaxf(fmaxf(wm[0], wm[1]), fmaxf(wm[2], wm[3]));
        atomicMax((int*)maxC, __float_as_int(m));  // C >= 0 so int-bit compare is order-preserving
    }
}

// ---------------- init: logp, logq, qmul ----------------
__global__ __launch_bounds__(256) void init_k(const float* __restrict__ p, const float* __restrict__ q,
                                              float* __restrict__ logp, float* __restrict__ logq,
                                              float* __restrict__ qmul, const float* __restrict__ maxC) {
    int i = blockIdx.x * 256 + threadIdx.x;
    if (i < N) {
        logp[i] = __logf(p[i]);
        logq[i] = __logf(q[i]);
    }
    if (i == 0) *qmul = 65535.0f / (*maxC);
}

// ---------------- quantize C to uint16, write row-major + transposed ----------------
__global__ __launch_bounds__(256) void quant_t_k(const float* __restrict__ C,
                                                 unsigned short* __restrict__ Mq,
                                                 unsigned short* __restrict__ Mqt,
                                                 const float* __restrict__ qmul_p) {
    __shared__ unsigned short tile[64][66];  // pad 2 shorts: 8-row LDS stride -> 2 lanes/bank (free)
    const float qmul = *qmul_p;
    const int bx = blockIdx.x & 63;   // col tile
    const int by = blockIdx.x >> 6;   // row tile
    const int t = threadIdx.x;
    const int tx = t & 15, ty = t >> 4;
    const int c0 = bx * 64, r0 = by * 64;

#pragma unroll
    for (int k = 0; k < 4; ++k) {
        int r = ty + k * 16;
        float4 cv = *(const float4*)(C + (size_t)(r0 + r) * N + c0 + tx * 4);
        unsigned q0 = min(65535u, __float2uint_rn(cv.x * qmul));
        unsigned q1 = min(65535u, __float2uint_rn(cv.y * qmul));
        unsigned q2 = min(65535u, __float2uint_rn(cv.z * qmul));
        unsigned q3 = min(65535u, __float2uint_rn(cv.w * qmul));
        uint2 pk;
        pk.x = q0 | (q1 << 16);
        pk.y = q2 | (q3 << 16);
        *(uint2*)(Mq + (size_t)(r0 + r) * N + c0 + tx * 4) = pk;
        tile[r][tx * 4 + 0] = (unsigned short)q0;
        tile[r][tx * 4 + 1] = (unsigned short)q1;
        tile[r][tx * 4 + 2] = (unsigned short)q2;
        tile[r][tx * 4 + 3] = (unsigned short)q3;
    }
    __syncthreads();
    // transposed writes: task = i*8+g -> Mqt row (c0+i), cols [r0+8g, r0+8g+8)
#pragma unroll
    for (int task = t; task < 512; task += 256) {
        int i = task >> 3;
        int g = task & 7;
        unsigned short e0 = tile[g * 8 + 0][i], e1 = tile[g * 8 + 1][i];
        unsigned short e2 = tile[g * 8 + 2][i], e3 = tile[g * 8 + 3][i];
        unsigned short e4 = tile[g * 8 + 4][i], e5 = tile[g * 8 + 5][i];
        unsigned short e6 = tile[g * 8 + 6][i], e7 = tile[g * 8 + 7][i];
        uint4 o;
        o.x = (unsigned)e0 | ((unsigned)e1 << 16);
        o.y = (unsigned)e2 | ((unsigned)e3 << 16);
        o.z = (unsigned)e4 | ((unsigned)e5 << 16);
        o.w = (unsigned)e6 | ((unsigned)e7 << 16);
        *(uint4*)(Mqt + (size_t)(c0 + i) * N + r0 + g * 8) = o;
    }
}

// ---------------- one LSE pass, 2 rows per block ----------------
// outp[row] = logw[row] - log( sum_j exp( -q[row][j]*DSTEP + other[j] ) )
__global__ __launch_bounds__(256) void lse2(const unsigned short* __restrict__ Mq,
                                            const float* __restrict__ other,
                                            const float* __restrict__ logw,
                                            float* __restrict__ outp) {
    const int t = threadIdx.x;
    const int row0 = blockIdx.x << 1;
    const uint4* m0 = (const uint4*)(Mq + (size_t)row0 * N);        // 512 uint4 per row
    const uint4* m1 = (const uint4*)(Mq + (size_t)(row0 + 1) * N);
    const float4* ov = (const float4*)other;

    // thread t covers columns [16t, 16t+16)
    float w[16];
#pragma unroll
    for (int k = 0; k < 4; ++k) {
        float4 f = ov[4 * t + k];
        w[4 * k + 0] = f.x; w[4 * k + 1] = f.y; w[4 * k + 2] = f.z; w[4 * k + 3] = f.w;
    }
    float s0 = 0.f, s1 = 0.f;
#pragma unroll
    for (int g = 0; g < 2; ++g) {
        uint4 a = m0[2 * t + g];
        uint4 b = m1[2 * t + g];
        const unsigned av[4] = {a.x, a.y, a.z, a.w};
        const unsigned bv[4] = {b.x, b.y, b.z, b.w};
#pragma unroll
        for (int d = 0; d < 4; ++d) {
            float wlo = w[8 * g + 2 * d], whi = w[8 * g + 2 * d + 1];
            s0 += __expf(fmaf((float)(av[d] & 0xffffu), -DSTEP, wlo));
            s0 += __expf(fmaf((float)(av[d] >> 16), -DSTEP, whi));
            s1 += __expf(fmaf((float)(bv[d] & 0xffffu), -DSTEP, wlo));
            s1 += __expf(fmaf((float)(bv[d] >> 16), -DSTEP, whi));
        }
    }
#pragma unroll
    for (int off = 32; off; off >>= 1) {
        s0 += __shfl_down(s0, off);
        s1 += __shfl_down(s1, off);
    }
    __shared__ float l0[4], l1[4];
    if ((t & 63) == 0) {
        l0[t >> 6] = s0;
        l1[t >> 6] = s1;
    }
    __syncthreads();
    if (t == 0) outp[row0] = logw[row0] - __logf((l0[0] + l0[1]) + (l0[2] + l0[3]));
    if (t == 1) outp[row0 + 1] = logw[row0 + 1] - __logf((l1[0] + l1[1]) + (l1[2] + l1[3]));
}

// ---------------- final plan from quantized Mr ----------------
__global__ __launch_bounds__(256) void final_k(const unsigned short* __restrict__ Mq,
                                               const float* __restrict__ u,
                                               const float* __restrict__ v,
                                               float* __restrict__ out) {
    const size_t i8 = (size_t)blockIdx.x * 256 + threadIdx.x;  // ushort8 index, N*N/8 total
    const uint4 a = ((const uint4*)Mq)[i8];
    const int row = (int)(i8 >> 9);          // 512 groups per row
    const int c = (int)(i8 & 511) * 8;
    const float uu = u[row];
    const float4 v0 = *(const float4*)(v + c);
    const float4 v1 = *(const float4*)(v + c + 4);
    float4 o0, o1;
    o0.x = __expf(fmaf((float)(a.x & 0xffffu), -DSTEP, uu + v0.x));
    o0.y = __expf(fmaf((float)(a.x >> 16), -DSTEP, uu + v0.y));
    o0.z = __expf(fmaf((float)(a.y & 0xffffu), -DSTEP, uu + v0.z));
    o0.w = __expf(fmaf((float)(a.y >> 16), -DSTEP, uu + v0.w));
    o1.x = __expf(fmaf((float)(a.z & 0xffffu), -DSTEP, uu + v1.x));
    o1.y = __expf(fmaf((float)(a.z >> 16), -DSTEP, uu + v1.y));
    o1.z = __expf(fmaf((float)(a.w & 0xffffu), -DSTEP, uu + v1.z));
    o1.w = __expf(fmaf((float)(a.w >> 16), -DSTEP, uu + v1.w));
    *(float4*)(out + (size_t)row * N + c) = o0;
    *(float4*)(out + (size_t)row * N + c + 4) = o1;
}

extern "C" void kernel_launch(void* const* d_in, const int* in_sizes, int n_in,
                              void* d_out, int out_size, void* d_ws, size_t ws_size,
                              hipStream_t stream) {
    const float* p = (const float*)d_in[0];
    const float* q = (const float*)d_in[1];
    const float* C = (const float*)d_in[2];
    float* out = (float*)d_out;

    float* W = (float*)d_ws;
    float* maxC = W + 0;
    float* qmul = W + 1;
    float* v = W + 8;          // needs zero init
    float* u = v + N;
    float* logp = u + N;
    float* logq = logp + N;

    const size_t HDR = 128 * 1024;  // bytes reserved for header
    unsigned short* Mq = (unsigned short*)((char*)d_ws + HDR);
    unsigned short* Mqt = Mq + (size_t)N * N;

    // zero maxC..v (covers maxC, qmul, pad, v)
    hipMemsetAsync(d_ws, 0, (8 + (size_t)N) * sizeof(float), stream);

    max_k<<<2048, 256, 0, stream>>>(C, maxC);
    init_k<<<16, 256, 0, stream>>>(p, q, logp, logq, qmul, maxC);
    quant_t_k<<<4096, 256, 0, stream>>>(C, Mq, Mqt, qmul);

    for (int it = 0; it < NITER; ++it) {
        lse2<<<N / 2, 256, 0, stream>>>(Mq, v, logp, u);    // u update (rows)
        lse2<<<N / 2, 256, 0, stream>>>(Mqt, u, logq, v);   // v update (cols via transpose)
    }

    final_k<<<8192, 256, 0, stream>>>(Mq, u, v, out);
}

// Round 3
// 568.027 us; speedup vs baseline: 4.0037x; 2.7265x over previous
//
#include <hip/hip_runtime.h>

#define N 4096
#define NITER 100
// Mr = -(C/maxC)/0.05 in [-20,0]; q16 = round((C/maxC)*65535); Mr ~= -q16*DSTEP
#define DSTEP (20.0f / 65535.0f)
#define TOL 1e-5f
#define NREP 8

typedef unsigned short u16;
typedef unsigned int u32;

// ---------------- global max of C ----------------
__global__ __launch_bounds__(256) void max_k(const float* __restrict__ C, float* __restrict__ maxC) {
    const float4* C4 = (const float4*)C;
    const size_t n4 = (size_t)N * N / 4;
    float m = 0.f;
    for (size_t i = (size_t)blockIdx.x * 256 + threadIdx.x; i < n4; i += (size_t)gridDim.x * 256) {
        float4 c = C4[i];
        m = fmaxf(m, fmaxf(fmaxf(c.x, c.y), fmaxf(c.z, c.w)));
    }
#pragma unroll
    for (int off = 32; off; off >>= 1) m = fmaxf(m, __shfl_down(m, off));
    __shared__ float wm[4];
    if ((threadIdx.x & 63) == 0) wm[threadIdx.x >> 6] = m;
    __syncthreads();
    if (threadIdx.x == 0) {
        m = fmaxf(fmaxf(wm[0], wm[1]), fmaxf(wm[2], wm[3]));
        atomicMax((int*)maxC, __float_as_int(m));  // C >= 0: int-bit compare order-preserving
    }
}

// ---------------- init: logp, logq, qmul ----------------
__global__ __launch_bounds__(256) void init_k(const float* __restrict__ p, const float* __restrict__ q,
                                              float* __restrict__ logp, float* __restrict__ logq,
                                              float* __restrict__ qmul, const float* __restrict__ maxC) {
    int i = blockIdx.x * 256 + threadIdx.x;
    if (i < N) {
        logp[i] = __logf(p[i]);
        logq[i] = __logf(q[i]);
    }
    if (i == 0) *qmul = 65535.0f / (*maxC);
}

// ---------------- quantize C to uint16 (row-major only) ----------------
__global__ __launch_bounds__(256) void quant_k(const float* __restrict__ C,
                                               u16* __restrict__ Mq,
                                               const float* __restrict__ qmul_p) {
    const float qmul = *qmul_p;
    const size_t i = (size_t)blockIdx.x * 256 + threadIdx.x;  // 8 elems per thread
    const float4* C4 = (const float4*)C;
    float4 a = C4[2 * i], b = C4[2 * i + 1];
    uint4 o;
    o.x = min(65535u, __float2uint_rn(a.x * qmul)) | (min(65535u, __float2uint_rn(a.y * qmul)) << 16);
    o.y = min(65535u, __float2uint_rn(a.z * qmul)) | (min(65535u, __float2uint_rn(a.w * qmul)) << 16);
    o.z = min(65535u, __float2uint_rn(b.x * qmul)) | (min(65535u, __float2uint_rn(b.y * qmul)) << 16);
    o.w = min(65535u, __float2uint_rn(b.z * qmul)) | (min(65535u, __float2uint_rn(b.w * qmul)) << 16);
    ((uint4*)Mq)[i] = o;
}

// ---------------- fused Sinkhorn iteration: u-update + col accumulation + v-finalize ----------------
// Block b owns rows [16b,16b+16). Thread t owns cols [4t,4t+4).
// For each row r: t_rj = exp(-q16*DSTEP + v_old_j); S_r = sum_j t_rj;
//   u_r = logp_r - log S_r;  colacc_j += t_rj * (p_r/S_r)
// Last block: v_new_j = logq_j + v_old_j - log(sum_reps acc_j); conv check; zero acc.
__global__ __launch_bounds__(1024) void sink_iter(const u16* __restrict__ Mq,
                                                  const float* __restrict__ p,
                                                  const float* __restrict__ logp,
                                                  const float* __restrict__ logq,
                                                  float* __restrict__ u,
                                                  float* __restrict__ v,
                                                  float* __restrict__ acc,
                                                  u32* __restrict__ counter,
                                                  int* __restrict__ flag) {
    if (__hip_atomic_load(flag, __ATOMIC_RELAXED, __HIP_MEMORY_SCOPE_AGENT)) return;
    const int t = threadIdx.x;
    const int lane = t & 63;
    const int wave = t >> 6;      // 0..15
    const int c0 = t * 4;
    const int r0 = blockIdx.x * 16;

    const float4 vo = *(const float4*)(v + c0);
    float ca0 = 0.f, ca1 = 0.f, ca2 = 0.f, ca3 = 0.f;

    __shared__ float sred[8][16];
    __shared__ float wbc[8];

    for (int ch = 0; ch < 2; ++ch) {
        const int rbase = r0 + ch * 8;
        float tq0[8], tq1[8], tq2[8], tq3[8], sp[8];
#pragma unroll
        for (int r = 0; r < 8; ++r) {
            uint2 pk = *(const uint2*)(Mq + (size_t)(rbase + r) * N + c0);
            float e0 = __expf(fmaf((float)(pk.x & 0xffffu), -DSTEP, vo.x));
            float e1 = __expf(fmaf((float)(pk.x >> 16),     -DSTEP, vo.y));
            float e2 = __expf(fmaf((float)(pk.y & 0xffffu), -DSTEP, vo.z));
            float e3 = __expf(fmaf((float)(pk.y >> 16),     -DSTEP, vo.w));
            tq0[r] = e0; tq1[r] = e1; tq2[r] = e2; tq3[r] = e3;
            sp[r] = (e0 + e1) + (e2 + e3);
        }
        // wave-reduce each row's partial
#pragma unroll
        for (int r = 0; r < 8; ++r) {
            float s = sp[r];
#pragma unroll
            for (int off = 32; off; off >>= 1) s += __shfl_down(s, off);
            if (lane == 0) sred[r][wave] = s;
        }
        __syncthreads();
        // waves 0..7: wave w finishes row rbase+w
        if (wave < 8) {
            float s = (lane < 16) ? sred[wave][lane] : 0.f;
#pragma unroll
            for (int off = 8; off; off >>= 1) s += __shfl_down(s, off);
            if (lane == 0) {
                const int rr = rbase + wave;
                wbc[wave] = p[rr] / s;           // exp(u_new_r)
                u[rr] = logp[rr] - __logf(s);
            }
        }
        __syncthreads();
#pragma unroll
        for (int r = 0; r < 8; ++r) {
            const float w = wbc[r];
            ca0 = fmaf(tq0[r], w, ca0);
            ca1 = fmaf(tq1[r], w, ca1);
            ca2 = fmaf(tq2[r], w, ca2);
            ca3 = fmaf(tq3[r], w, ca3);
        }
        // chunk-1 sred/wbc writes are separated from chunk-0 reads by the two syncs above
    }

    float* arep = acc + (size_t)(blockIdx.x & (NREP - 1)) * N;
    atomicAdd(arep + c0 + 0, ca0);
    atomicAdd(arep + c0 + 1, ca1);
    atomicAdd(arep + c0 + 2, ca2);
    atomicAdd(arep + c0 + 3, ca3);
    __threadfence();
    __shared__ u32 ticket;
    if (t == 0) ticket = atomicAdd(counter, 1u);
    __syncthreads();
    if (ticket != gridDim.x - 1) return;

    // ---- finisher block ----
    float s0 = 0.f, s1 = 0.f, s2 = 0.f, s3 = 0.f;
#pragma unroll
    for (int rep = 0; rep < NREP; ++rep) {
        const float* a = acc + (size_t)rep * N + c0;
        s0 += __hip_atomic_load(a + 0, __ATOMIC_RELAXED, __HIP_MEMORY_SCOPE_AGENT);
        s1 += __hip_atomic_load(a + 1, __ATOMIC_RELAXED, __HIP_MEMORY_SCOPE_AGENT);
        s2 += __hip_atomic_load(a + 2, __ATOMIC_RELAXED, __HIP_MEMORY_SCOPE_AGENT);
        s3 += __hip_atomic_load(a + 3, __ATOMIC_RELAXED, __HIP_MEMORY_SCOPE_AGENT);
    }
    float4 vn;
    vn.x = logq[c0 + 0] + vo.x - __logf(s0);
    vn.y = logq[c0 + 1] + vo.y - __logf(s1);
    vn.z = logq[c0 + 2] + vo.z - __logf(s2);
    vn.w = logq[c0 + 3] + vo.w - __logf(s3);
    *(float4*)(v + c0) = vn;
    const float4 z = {0.f, 0.f, 0.f, 0.f};
#pragma unroll
    for (int rep = 0; rep < NREP; ++rep) *(float4*)(acc + (size_t)rep * N + c0) = z;

    float d = fmaxf(fmaxf(fabsf(vn.x - vo.x), fabsf(vn.y - vo.y)),
                    fmaxf(fabsf(vn.z - vo.z), fabsf(vn.w - vo.w)));
#pragma unroll
    for (int off = 32; off; off >>= 1) d = fmaxf(d, __shfl_down(d, off));
    __shared__ float dred[16];
    if (lane == 0) dred[wave] = d;
    __syncthreads();
    if (t == 0) {
        float dm = dred[0];
#pragma unroll
        for (int wv = 1; wv < 16; ++wv) dm = fmaxf(dm, dred[wv]);
        if (dm < TOL) __hip_atomic_store(flag, 1, __ATOMIC_RELAXED, __HIP_MEMORY_SCOPE_AGENT);
        *counter = 0u;
    }
}

// ---------------- final plan from quantized Mr ----------------
__global__ __launch_bounds__(256) void final_k(const u16* __restrict__ Mq,
                                               const float* __restrict__ u,
                                               const float* __restrict__ v,
                                               float* __restrict__ out) {
    const size_t i8 = (size_t)blockIdx.x * 256 + threadIdx.x;  // ushort8 group
    const uint4 a = ((const uint4*)Mq)[i8];
    const int row = (int)(i8 >> 9);
    const int c = (int)(i8 & 511) * 8;
    const float uu = u[row];
    const float4 v0 = *(const float4*)(v + c);
    const float4 v1 = *(const float4*)(v + c + 4);
    float4 o0, o1;
    o0.x = __expf(fmaf((float)(a.x & 0xffffu), -DSTEP, uu + v0.x));
    o0.y = __expf(fmaf((float)(a.x >> 16), -DSTEP, uu + v0.y));
    o0.z = __expf(fmaf((float)(a.y & 0xffffu), -DSTEP, uu + v0.z));
    o0.w = __expf(fmaf((float)(a.y >> 16), -DSTEP, uu + v0.w));
    o1.x = __expf(fmaf((float)(a.z & 0xffffu), -DSTEP, uu + v1.x));
    o1.y = __expf(fmaf((float)(a.z >> 16), -DSTEP, uu + v1.y));
    o1.z = __expf(fmaf((float)(a.w & 0xffffu), -DSTEP, uu + v1.z));
    o1.w = __expf(fmaf((float)(a.w >> 16), -DSTEP, uu + v1.w));
    *(float4*)(out + (size_t)row * N + c) = o0;
    *(float4*)(out + (size_t)row * N + c + 4) = o1;
}

extern "C" void kernel_launch(void* const* d_in, const int* in_sizes, int n_in,
                              void* d_out, int out_size, void* d_ws, size_t ws_size,
                              hipStream_t stream) {
    const float* p = (const float*)d_in[0];
    const float* q = (const float*)d_in[1];
    const float* C = (const float*)d_in[2];
    float* out = (float*)d_out;

    float* W = (float*)d_ws;
    float* maxC = W + 0;
    float* qmul = W + 1;
    u32* counter = (u32*)(W + 2);
    int* flag = (int*)(W + 3);
    float* v = W + 16;                 // 4096, must start 0
    float* acc = v + N;                // 8*4096, must start 0
    float* u = acc + NREP * N;         // 4096
    float* logp = u + N;               // 4096
    float* logq = logp + N;            // 4096

    const size_t HDR = 256 * 1024;
    u16* Mq = (u16*)((char*)d_ws + HDR);

    // zero header through acc (maxC,qmul,counter,flag,pad,v,acc)
    hipMemsetAsync(d_ws, 0, (size_t)(16 + N + NREP * N) * sizeof(float), stream);

    max_k<<<2048, 256, 0, stream>>>(C, maxC);
    init_k<<<16, 256, 0, stream>>>(p, q, logp, logq, qmul, maxC);
    quant_k<<<N * N / 8 / 256, 256, 0, stream>>>(C, Mq, qmul);

    for (int it = 0; it < NITER; ++it)
        sink_iter<<<256, 1024, 0, stream>>>(Mq, p, logp, logq, u, v, acc, counter, flag);

    final_k<<<N * N / 8 / 256, 256, 0, stream>>>(Mq, u, v, out);
}

// Round 4
// 401.555 us; speedup vs baseline: 5.6635x; 1.4146x over previous
//
#include <hip/hip_runtime.h>
#include <hip/hip_cooperative_groups.h>

namespace cg = cooperative_groups;

#define N 4096
#define NITER 100
// Mr = -(C/maxC)/0.05 in [-20,0]; q16 = round((C/maxC)*65535); Mr ~= -q16*DSTEP
#define DSTEP (20.0f / 65535.0f)
#define TOL 1e-5f
#define NB 256
#define NT 512

typedef unsigned short u16;
typedef unsigned int u32;

// One persistent cooperative kernel does everything:
//   phase 0: max(C)            -> grid.sync
//   phase 1: quantize, init    -> grid.sync
//   loop: A (u-update + column partials, plain stores)  -> grid.sync
//         B (reduce partials -> v-update, per-block delta) -> grid.sync
//         uniform convergence check -> break
//   final: out = exp(-q*DSTEP + u + v)
__global__ __launch_bounds__(NT) void ot_all(const float* __restrict__ p,
                                             const float* __restrict__ q,
                                             const float* __restrict__ C,
                                             float* __restrict__ maxC,
                                             float* __restrict__ u,
                                             float* __restrict__ v,
                                             float* __restrict__ logp,
                                             float* __restrict__ logq,
                                             float* __restrict__ part,
                                             float* __restrict__ ddel,
                                             u16* __restrict__ Mq,
                                             float* __restrict__ out) {
    cg::grid_group grid = cg::this_grid();
    const int t = threadIdx.x;
    const int b = blockIdx.x;
    const int lane = t & 63;
    const int wave = t >> 6;            // 0..7
    const int gid = b * NT + t;         // 0..131071

    // ---------------- phase 0: max(C) ----------------
    {
        const float4* C4 = (const float4*)C;
        float m = 0.f;
        for (int i = gid; i < N * N / 4; i += NB * NT) {
            float4 c = C4[i];
            m = fmaxf(m, fmaxf(fmaxf(c.x, c.y), fmaxf(c.z, c.w)));
        }
#pragma unroll
        for (int off = 32; off; off >>= 1) m = fmaxf(m, __shfl_down(m, off));
        __shared__ float wm[8];
        if (lane == 0) wm[wave] = m;
        __syncthreads();
        if (t == 0) {
            m = wm[0];
#pragma unroll
            for (int i = 1; i < 8; ++i) m = fmaxf(m, wm[i]);
            atomicMax((int*)maxC, __float_as_int(m));  // C >= 0: int order == float order
        }
    }
    grid.sync();
    const float qmul = 65535.0f / *maxC;

    // ---------------- phase 1: quantize + vector init ----------------
    {
        const float4* C4 = (const float4*)C;
        uint4* M4 = (uint4*)Mq;
        for (int i = gid; i < N * N / 8; i += NB * NT) {
            float4 a = C4[2 * i], bb = C4[2 * i + 1];
            uint4 o;
            o.x = min(65535u, __float2uint_rn(a.x * qmul)) | (min(65535u, __float2uint_rn(a.y * qmul)) << 16);
            o.y = min(65535u, __float2uint_rn(a.z * qmul)) | (min(65535u, __float2uint_rn(a.w * qmul)) << 16);
            o.z = min(65535u, __float2uint_rn(bb.x * qmul)) | (min(65535u, __float2uint_rn(bb.y * qmul)) << 16);
            o.w = min(65535u, __float2uint_rn(bb.z * qmul)) | (min(65535u, __float2uint_rn(bb.w * qmul)) << 16);
            M4[i] = o;
        }
        if (gid < N) {
            logp[gid] = __logf(p[gid]);
            logq[gid] = __logf(q[gid]);
            v[gid] = 0.f;
        }
    }
    grid.sync();

    // ---------------- Sinkhorn iterations ----------------
    const int j0 = t * 8;       // phase-A column base (512 threads x 8 cols = 4096)
    const int c0 = b * 16;      // phase-B column base (256 blocks x 16 cols = 4096)
    const int r0 = b * 16;      // phase-A row base   (256 blocks x 16 rows = 4096)

    __shared__ float sred[4][8];
    __shared__ float wbc[4];
    __shared__ float s2[16][8];
    __shared__ float dm[8];

    for (int it = 0; it < NITER; ++it) {
        // ---- phase A: t_rj = exp(-q16*DSTEP + v_j); S_r; u_r = logp_r - log S_r;
        //      colpart_j += t_rj * (p_r / S_r)  (per-block, plain stores) ----
        float vv[8];
        *(float4*)(vv) = *(const float4*)(v + j0);
        *(float4*)(vv + 4) = *(const float4*)(v + j0 + 4);
        float ca[8];
#pragma unroll
        for (int k = 0; k < 8; ++k) ca[k] = 0.f;

        for (int ch = 0; ch < 4; ++ch) {
            const int rbase = r0 + ch * 4;
            float tq[4][8], sp[4];
#pragma unroll
            for (int r = 0; r < 4; ++r) {
                uint4 a = *(const uint4*)(Mq + (size_t)(rbase + r) * N + j0);
                float e0 = __expf(fmaf((float)(a.x & 0xffffu), -DSTEP, vv[0]));
                float e1 = __expf(fmaf((float)(a.x >> 16),     -DSTEP, vv[1]));
                float e2 = __expf(fmaf((float)(a.y & 0xffffu), -DSTEP, vv[2]));
                float e3 = __expf(fmaf((float)(a.y >> 16),     -DSTEP, vv[3]));
                float e4 = __expf(fmaf((float)(a.z & 0xffffu), -DSTEP, vv[4]));
                float e5 = __expf(fmaf((float)(a.z >> 16),     -DSTEP, vv[5]));
                float e6 = __expf(fmaf((float)(a.w & 0xffffu), -DSTEP, vv[6]));
                float e7 = __expf(fmaf((float)(a.w >> 16),     -DSTEP, vv[7]));
                tq[r][0] = e0; tq[r][1] = e1; tq[r][2] = e2; tq[r][3] = e3;
                tq[r][4] = e4; tq[r][5] = e5; tq[r][6] = e6; tq[r][7] = e7;
                sp[r] = ((e0 + e1) + (e2 + e3)) + ((e4 + e5) + (e6 + e7));
            }
#pragma unroll
            for (int r = 0; r < 4; ++r) {
                float s = sp[r];
#pragma unroll
                for (int off = 32; off; off >>= 1) s += __shfl_down(s, off);
                if (lane == 0) sred[r][wave] = s;
            }
            __syncthreads();
            if (wave < 4) {  // wave w finalizes row rbase+w
                float s = (lane < 8) ? sred[wave][lane] : 0.f;
                s += __shfl_down(s, 4);
                s += __shfl_down(s, 2);
                s += __shfl_down(s, 1);
                if (lane == 0) {
                    const int rr = rbase + wave;
                    wbc[wave] = p[rr] / s;             // exp(u_new_r)
                    u[rr] = logp[rr] - __logf(s);
                }
            }
            __syncthreads();
#pragma unroll
            for (int r = 0; r < 4; ++r) {
                const float w = wbc[r];
#pragma unroll
                for (int k = 0; k < 8; ++k) ca[k] = fmaf(tq[r][k], w, ca[k]);
            }
        }
        *(float4*)(part + (size_t)b * N + j0) = *(float4*)(ca);
        *(float4*)(part + (size_t)b * N + j0 + 4) = *(float4*)(ca + 4);
        grid.sync();

        // ---- phase B: v_j = logq_j + v_old_j - log( sum_b part[b][j] ) for 16 owned cols ----
        {
            const int cl = t & 15;        // 0..15 col-local
            const int rr = t >> 4;        // 0..31 part-row
            const int c = c0 + cl;
            float s = 0.f;
#pragma unroll
            for (int k = 0; k < 8; ++k) s += part[(size_t)(rr + 32 * k) * N + c];
            // reduce over the 4 rr's living in this wave (lane = (rr&3)*16 + cl)
            s += __shfl_down(s, 16);
            s += __shfl_down(s, 32);
            if ((lane >> 4) == 0) s2[cl][wave] = s;
            __syncthreads();
            if (t < 16) {
                float tot = 0.f;
#pragma unroll
                for (int w = 0; w < 8; ++w) tot += s2[t][w];
                const float vold = v[c0 + t];
                const float vn = logq[c0 + t] + vold - __logf(tot);
                v[c0 + t] = vn;
                float d = fabsf(vn - vold);
                d = fmaxf(d, __shfl_down(d, 8));
                d = fmaxf(d, __shfl_down(d, 4));
                d = fmaxf(d, __shfl_down(d, 2));
                d = fmaxf(d, __shfl_down(d, 1));
                if (t == 0) ddel[b] = d;
            }
        }
        grid.sync();

        // ---- uniform convergence check ----
        {
            float d = ddel[t & 255];
#pragma unroll
            for (int off = 32; off; off >>= 1) d = fmaxf(d, __shfl_down(d, off));
            if (lane == 0) dm[wave] = d;
            __syncthreads();
            const float m = fmaxf(fmaxf(fmaxf(dm[0], dm[1]), fmaxf(dm[2], dm[3])),
                                  fmaxf(fmaxf(dm[4], dm[5]), fmaxf(dm[6], dm[7])));
            __syncthreads();
            if (m < TOL) break;   // same data in every block -> uniform
        }
    }

    // ---------------- final: out = exp(-q*DSTEP + u + v) ----------------
    {
        const uint4* M4 = (const uint4*)Mq;
        for (int i = gid; i < N * N / 8; i += NB * NT) {
            uint4 a = M4[i];
            const int row = i >> 9;           // 512 ushort8-groups per row
            const int c = (i & 511) * 8;
            const float uu = u[row];
            const float4 v0 = *(const float4*)(v + c);
            const float4 v1 = *(const float4*)(v + c + 4);
            float4 o0, o1;
            o0.x = __expf(fmaf((float)(a.x & 0xffffu), -DSTEP, uu + v0.x));
            o0.y = __expf(fmaf((float)(a.x >> 16),     -DSTEP, uu + v0.y));
            o0.z = __expf(fmaf((float)(a.y & 0xffffu), -DSTEP, uu + v0.z));
            o0.w = __expf(fmaf((float)(a.y >> 16),     -DSTEP, uu + v0.w));
            o1.x = __expf(fmaf((float)(a.z & 0xffffu), -DSTEP, uu + v1.x));
            o1.y = __expf(fmaf((float)(a.z >> 16),     -DSTEP, uu + v1.y));
            o1.z = __expf(fmaf((float)(a.w & 0xffffu), -DSTEP, uu + v1.z));
            o1.w = __expf(fmaf((float)(a.w >> 16),     -DSTEP, uu + v1.w));
            *(float4*)(out + (size_t)row * N + c) = o0;
            *(float4*)(out + (size_t)row * N + c + 4) = o1;
        }
    }
}

extern "C" void kernel_launch(void* const* d_in, const int* in_sizes, int n_in,
                              void* d_out, int out_size, void* d_ws, size_t ws_size,
                              hipStream_t stream) {
    const float* p = (const float*)d_in[0];
    const float* q = (const float*)d_in[1];
    const float* C = (const float*)d_in[2];
    float* out = (float*)d_out;

    float* W = (float*)d_ws;
    float* maxC = W + 0;                 // must start 0 (atomicMax target)
    float* u = W + 16;                   // N
    float* v = u + N;                    // N
    float* logp = v + N;                 // N
    float* logq = logp + N;              // N
    float* ddel = logq + N;              // NB

    float* part = (float*)((char*)d_ws + 128 * 1024);          // NB x N f32 = 4 MB
    u16* Mq = (u16*)((char*)d_ws + 128 * 1024 + (size_t)NB * N * sizeof(float));  // 32 MB

    hipMemsetAsync(d_ws, 0, 64, stream);  // zero maxC

    void* args[] = {(void*)&p, (void*)&q, (void*)&C, (void*)&maxC, (void*)&u, (void*)&v,
                    (void*)&logp, (void*)&logq, (void*)&part, (void*)&ddel, (void*)&Mq, (void*)&out};
    hipLaunchCooperativeKernel((void*)ot_all, dim3(NB), dim3(NT), args, 0, stream);
}

// Round 6
// 378.726 us; speedup vs baseline: 6.0049x; 1.0603x over previous
//
#include <hip/hip_runtime.h>
#include <hip/hip_cooperative_groups.h>

namespace cg = cooperative_groups;

#define N 4096
#define NITER 100
// Mr = -(C/maxC)/0.05 in [-20,0]; q16 = round((C/maxC)*65535); Mr ~= -q16*DSTEP
#define DSTEP (20.0f / 65535.0f)
#define LOG2E 1.44269504088896340736f
#define DSTEP2 (DSTEP * LOG2E)
#define TOL 1e-5f
#define NB 256
#define NT 1024
#define ROWS 16                      // rows of Mq owned per block, resident in LDS
#define TILE_BYTES (ROWS * N * 2)    // 128 KiB

typedef unsigned short u16;

// Cross-XCD-coherent accessors (per-XCD L2 is NOT coherent; sc1/agent-scope
// atomics read/write at the device coherence point). ALL cross-block
// communication must use these — plain loads after grid.sync can see stale L2
// lines (round-5 post-timing divergence).
__device__ __forceinline__ float aload(const float* p) {
    return __hip_atomic_load(p, __ATOMIC_RELAXED, __HIP_MEMORY_SCOPE_AGENT);
}
__device__ __forceinline__ void astore(float* p, float x) {
    __hip_atomic_store(p, x, __ATOMIC_RELAXED, __HIP_MEMORY_SCOPE_AGENT);
}

__device__ __forceinline__ float fexp2(float x) {
#if __has_builtin(__builtin_amdgcn_exp2f)
    return __builtin_amdgcn_exp2f(x);        // raw v_exp_f32
#else
    return __expf(x * 0.6931471805599453f);  // exp(x*ln2) == 2^x
#endif
}

// One persistent cooperative kernel:
//   phase 0: max(C)                                   -> grid.sync
//   phase 1: quantize own 16 rows into LDS; init      -> grid.sync
//   loop: A (u-update in LDS + per-block col partials) -> grid.sync
//         B (reduce partials -> v-update, delta)       -> grid.sync
//         uniform convergence check -> break
//   final: out rows = exp(-q*DSTEP + u + v) from LDS tile
__global__ __launch_bounds__(NT) void ot_all(const float* __restrict__ p,
                                             const float* __restrict__ q,
                                             const float* __restrict__ C,
                                             float* maxC,
                                             float* v,
                                             float* part,
                                             float* ddel,
                                             float* __restrict__ out) {
    cg::grid_group grid = cg::this_grid();
    extern __shared__ u16 tile[];        // [ROWS][N] = 128 KiB
    const int t = threadIdx.x;
    const int b = blockIdx.x;
    const int lane = t & 63;
    const int wave = t >> 6;             // 0..15
    const int gid = b * NT + t;
    const int r0 = b * ROWS;             // owned rows (phase A / final)
    const int c0 = b * 16;               // owned cols (phase B)
    const int j0 = t * 4;                // per-thread col slice

    __shared__ float sred[4][16];
    __shared__ float wbc[4];
    __shared__ float s2[16][16];
    __shared__ float dm[16];
    __shared__ float wm[16];
    __shared__ float lp[ROWS], pp[ROWS], lq[16], su[ROWS];

    // ---------------- phase 0: max(C) (C is read-only input -> plain loads OK) ----------------
    {
        const float4* C4 = (const float4*)C;
        float m = 0.f;
        for (int i = gid; i < N * N / 4; i += NB * NT) {
            float4 c = C4[i];
            m = fmaxf(m, fmaxf(fmaxf(c.x, c.y), fmaxf(c.z, c.w)));
        }
#pragma unroll
        for (int off = 32; off; off >>= 1) m = fmaxf(m, __shfl_down(m, off));
        if (lane == 0) wm[wave] = m;
        __syncthreads();
        if (t == 0) {
            m = wm[0];
#pragma unroll
            for (int i = 1; i < 16; ++i) m = fmaxf(m, wm[i]);
            atomicMax((int*)maxC, __float_as_int(m));  // C >= 0: int order == float order
        }
    }
    grid.sync();
    const float qmul = 65535.0f / aload(maxC);

    // ---------------- phase 1: quantize own rows into LDS + per-block scalars ----------------
    {
        const float4* Crow = (const float4*)(C + (size_t)r0 * N);
        uint2* T2 = (uint2*)tile;
        for (int i = t; i < ROWS * N / 4; i += NT) {
            float4 a = Crow[i];
            uint2 o;
            o.x = min(65535u, __float2uint_rn(a.x * qmul)) | (min(65535u, __float2uint_rn(a.y * qmul)) << 16);
            o.y = min(65535u, __float2uint_rn(a.z * qmul)) | (min(65535u, __float2uint_rn(a.w * qmul)) << 16);
            T2[i] = o;
        }
        if (t < ROWS) {                      // own-block scalars from read-only inputs
            float pv = p[r0 + t];
            pp[t] = pv;
            lp[t] = __logf(pv);
            lq[t] = __logf(q[c0 + t]);
        }
        if (gid < N) astore(&v[gid], 0.f);   // coherent v init
    }
    float vreg = 0.f;                        // own col's v (valid for t<16)
    grid.sync();

    // ---------------- Sinkhorn iterations ----------------
    for (int it = 0; it < NITER; ++it) {
        // ---- phase A: t_rj = exp(Mr+v_j); S_r; u_r -> su; colpart_j += t_rj*(p_r/S_r) ----
        float vv2[4];
#pragma unroll
        for (int k = 0; k < 4; ++k) vv2[k] = aload(&v[j0 + k]) * LOG2E;
        float ca[4] = {0.f, 0.f, 0.f, 0.f};

        for (int ch = 0; ch < 4; ++ch) {
            const int rl = ch * 4;
            float tq[4][4], sp[4];
#pragma unroll
            for (int r = 0; r < 4; ++r) {
                uint2 a = *(const uint2*)(tile + (size_t)(rl + r) * N + j0);
                float e0 = fexp2(fmaf((float)(a.x & 0xffffu), -DSTEP2, vv2[0]));
                float e1 = fexp2(fmaf((float)(a.x >> 16),     -DSTEP2, vv2[1]));
                float e2 = fexp2(fmaf((float)(a.y & 0xffffu), -DSTEP2, vv2[2]));
                float e3 = fexp2(fmaf((float)(a.y >> 16),     -DSTEP2, vv2[3]));
                tq[r][0] = e0; tq[r][1] = e1; tq[r][2] = e2; tq[r][3] = e3;
                sp[r] = (e0 + e1) + (e2 + e3);
            }
#pragma unroll
            for (int r = 0; r < 4; ++r) {
                float s = sp[r];
#pragma unroll
                for (int off = 32; off; off >>= 1) s += __shfl_down(s, off);
                if (lane == 0) sred[r][wave] = s;
            }
            __syncthreads();
            if (wave < 4) {  // wave w finalizes local row rl+w
                float s = (lane < 16) ? sred[wave][lane] : 0.f;
                s += __shfl_down(s, 8);
                s += __shfl_down(s, 4);
                s += __shfl_down(s, 2);
                s += __shfl_down(s, 1);
                if (lane == 0) {
                    wbc[wave] = pp[rl + wave] / s;             // exp(u_new_r)
                    su[rl + wave] = lp[rl + wave] - __logf(s); // u_new_r (block-local)
                }
            }
            __syncthreads();
#pragma unroll
            for (int r = 0; r < 4; ++r) {
                const float w = wbc[r];
#pragma unroll
                for (int k = 0; k < 4; ++k) ca[k] = fmaf(tq[r][k], w, ca[k]);
            }
        }
#pragma unroll
        for (int k = 0; k < 4; ++k) astore(&part[(size_t)b * N + j0 + k], ca[k]);
        grid.sync();

        // ---- phase B: v_j = logq_j + v_old_j - log( sum_b part[b][j] ) for 16 owned cols ----
        {
            const int cl = t & 15;       // col-local
            const int ch = t >> 4;       // 0..63 part-row group
            const int c = c0 + cl;
            float s = 0.f;
#pragma unroll
            for (int k = 0; k < 4; ++k) s += aload(&part[(size_t)(ch + 64 * k) * N + c]);
            s += __shfl_down(s, 16);
            s += __shfl_down(s, 32);
            if (lane < 16) s2[cl][wave] = s;
            __syncthreads();
            if (t < 16) {
                float tot = 0.f;
#pragma unroll
                for (int w = 0; w < 16; ++w) tot += s2[t][w];
                const float vn = lq[t] + vreg - __logf(tot);
                astore(&v[c0 + t], vn);
                float d = fabsf(vn - vreg);
                vreg = vn;                     // own col: only this block ever writes it
                d = fmaxf(d, __shfl_down(d, 8));
                d = fmaxf(d, __shfl_down(d, 4));
                d = fmaxf(d, __shfl_down(d, 2));
                d = fmaxf(d, __shfl_down(d, 1));
                if (t == 0) astore(&ddel[b], d);
            }
        }
        grid.sync();

        // ---- uniform convergence check (coherent ddel -> identical m in every block) ----
        {
            float d = aload(&ddel[t & 255]);
#pragma unroll
            for (int off = 32; off; off >>= 1) d = fmaxf(d, __shfl_down(d, off));
            if (lane == 0) dm[wave] = d;
            __syncthreads();
            float m = dm[0];
#pragma unroll
            for (int w = 1; w < 16; ++w) m = fmaxf(m, dm[w]);
            __syncthreads();
            if (m < TOL) break;
        }
    }

    // ---------------- final: out rows from LDS tile + su + coherent v ----------------
    {
        float vvl[4];
#pragma unroll
        for (int k = 0; k < 4; ++k) vvl[k] = aload(&v[j0 + k]) * LOG2E;
#pragma unroll 4
        for (int r = 0; r < ROWS; ++r) {
            const float uul = su[r] * LOG2E;
            uint2 a = *(const uint2*)(tile + (size_t)r * N + j0);
            float4 o;
            o.x = fexp2(fmaf((float)(a.x & 0xffffu), -DSTEP2, uul + vvl[0]));
            o.y = fexp2(fmaf((float)(a.x >> 16),     -DSTEP2, uul + vvl[1]));
            o.z = fexp2(fmaf((float)(a.y & 0xffffu), -DSTEP2, uul + vvl[2]));
            o.w = fexp2(fmaf((float)(a.y >> 16),     -DSTEP2, uul + vvl[3]));
            *(float4*)(out + (size_t)(r0 + r) * N + j0) = o;
        }
    }
}

extern "C" void kernel_launch(void* const* d_in, const int* in_sizes, int n_in,
                              void* d_out, int out_size, void* d_ws, size_t ws_size,
                              hipStream_t stream) {
    const float* p = (const float*)d_in[0];
    const float* q = (const float*)d_in[1];
    const float* C = (const float*)d_in[2];
    float* out = (float*)d_out;

    float* W = (float*)d_ws;
    float* maxC = W + 0;                 // must start 0 (atomicMax target)
    float* v = W + 16;                   // N
    float* ddel = v + N;                 // NB
    float* part = (float*)((char*)d_ws + 128 * 1024);   // NB x N f32 = 4 MB

    hipMemsetAsync(d_ws, 0, 64, stream);  // zero maxC

    hipFuncSetAttribute((const void*)ot_all, hipFuncAttributeMaxDynamicSharedMemorySize, TILE_BYTES);

    void* args[] = {(void*)&p, (void*)&q, (void*)&C, (void*)&maxC,
                    (void*)&v, (void*)&part, (void*)&ddel, (void*)&out};
    hipLaunchCooperativeKernel((void*)ot_all, dim3(NB), dim3(NT), args, TILE_BYTES, stream);
}